// Round 12
// baseline (300.867 us; speedup 1.0000x reference)
//
#include <hip/hip_runtime.h>

using f32x4  = __attribute__((ext_vector_type(4))) float;
using frag16 = __attribute__((ext_vector_type(8))) short;
using s16x4  = __attribute__((ext_vector_type(4))) short;
using s16x8  = __attribute__((ext_vector_type(8))) short;
using u32x4  = __attribute__((ext_vector_type(4))) unsigned;

#define DI __device__ __forceinline__

constexpr int HID  = 2048;
constexpr int NH   = 16;
constexpr int HD   = 128;
constexpr int TT   = 4096;   // total tokens
constexpr int SEQ  = 2048;
constexpr int NQKV = 3 * HID; // 6144
constexpr float SCL = 0.08838834764831845f * 1.4426950408889634f; // scale*log2e

DI short f2bf(float f) {
  unsigned u = __builtin_bit_cast(unsigned, f);
  unsigned r = (u + 0x7fffu + ((u >> 16) & 1u)) >> 16;
  return (short)r;
}
DI float bf2f(short s) {
  unsigned u = ((unsigned)(unsigned short)s) << 16;
  return __builtin_bit_cast(float, u);
}
DI unsigned cvtpk(float lo, float hi) {
  unsigned r;
  asm("v_cvt_pk_bf16_f32 %0, %1, %2" : "=v"(r) : "v"(lo), "v"(hi));
  return r;
}

// ---------------- merged prep: hidden conv + wqkv^T + wo^T (one launch) -----
struct alignas(8) S4h { short a, b, c, d; };

__global__ void prep(const float* __restrict__ hidden, short* __restrict__ Abf,
                     const float* __restrict__ wqkv, short* __restrict__ Wqkvt,
                     const float* __restrict__ wo, short* __restrict__ Wot) {
  __shared__ float t[64][65];
  const int bid = blockIdx.x;
  const int tid = threadIdx.x;
  if (bid < 8192) {                      // f32 -> bf16 convert of hidden
    int gid = bid * 256 + tid;
    float4 v = ((const float4*)hidden)[gid];
    S4h o{f2bf(v.x), f2bf(v.y), f2bf(v.z), f2bf(v.w)};
    ((S4h*)Abf)[gid] = o;
    return;
  }
  const float* in;
  short* out;
  int ldin, R, bx, by;
  if (bid < 8192 + 3072) {               // wqkv (2048 x 6144) -> (6144 x 2048)
    int idx = bid - 8192;
    in = wqkv; out = Wqkvt; ldin = NQKV; R = HID;
    bx = idx % 96; by = idx / 96;
  } else {                               // wo (2048 x 2048) -> (2048 x 2048)
    int idx = bid - 8192 - 3072;
    in = wo; out = Wot; ldin = HID; R = HID;
    bx = idx % 32; by = idx / 32;
  }
#pragma unroll
  for (int i = 0; i < 4; i++) {
    int idx = i * 256 + tid;
    int r = idx >> 4, c4 = idx & 15;
    size_t gi = (size_t)(by * 64 + r) * ldin + bx * 64 + c4 * 4;
    float4 v = *(const float4*)(in + gi);
    t[r][c4 * 4] = v.x; t[r][c4 * 4 + 1] = v.y;
    t[r][c4 * 4 + 2] = v.z; t[r][c4 * 4 + 3] = v.w;
  }
  __syncthreads();
#pragma unroll
  for (int i = 0; i < 4; i++) {
    int idx = i * 256 + tid;
    int r = idx >> 4, c4 = idx & 15;
    s16x4 o;
#pragma unroll
    for (int j = 0; j < 4; j++) o[j] = f2bf(t[c4 * 4 + j][r]);
    *(s16x4*)(out + (size_t)(bx * 64 + r) * R + by * 64 + c4 * 4) = o;
  }
}

// ---------------- bf16 transpose with attention token bit-perm --------------
// dest col c holds source token t(c) = (c>>5)*32 + ((c>>2)&1)*16 + ((c>>3)&3)*4 + (c&3)
__global__ void transpose_perm(const short* __restrict__ in, short* __restrict__ out,
                               int ldin, int R) {
  __shared__ float t[64][65];
  int tid = threadIdx.x;
  int bx = blockIdx.x, by = blockIdx.y;
#pragma unroll
  for (int i = 0; i < 4; i++) {
    int idx = i * 256 + tid;
    int r = idx >> 4, c4 = idx & 15;
    size_t gi = (size_t)(by * 64 + r) * ldin + bx * 64 + c4 * 4;
    s16x4 v = *(const s16x4*)(in + gi);
#pragma unroll
    for (int j = 0; j < 4; j++) t[r][c4 * 4 + j] = bf2f(v[j]);
  }
  __syncthreads();
#pragma unroll
  for (int i = 0; i < 4; i++) {
    int idx = i * 256 + tid;
    int r = idx >> 4, c4 = idx & 15;
    s16x4 o;
#pragma unroll
    for (int j = 0; j < 4; j++) {
      int c = c4 * 4 + j;
      int cs = (c >> 5) * 32 + ((c >> 2) & 1) * 16 + ((c >> 3) & 3) * 4 + (c & 3);
      o[j] = f2bf(t[cs][r]);
    }
    *(s16x4*)(out + (size_t)(bx * 64 + r) * R + by * 64 + c4 * 4) = o;
  }
}

#define GLDS(src, dst)                                                     \
  __builtin_amdgcn_global_load_lds(                                        \
      (const __attribute__((address_space(1))) void*)(src),                \
      (__attribute__((address_space(3))) void*)(dst), 16, 0, 0)

// ---------------- bf16 MFMA GEMM, B transposed (N x K), 128x128 tile ----------
// Wave cols remapped to {0,32,64,96}+wc*16 so (d, d+64) pairs are lane-local.
// EPI=0: plain f32 out. EPI=1: fused bias+RoPE epilogue (Qb, Kb+kc, vc+Vrow).
template <int EPI>
__global__ __launch_bounds__(256, 2) void gemm_bt(
    const short* __restrict__ A, const short* __restrict__ Bt,
    const float* __restrict__ bias, float* __restrict__ Cout,
    const float* __restrict__ cs, const float* __restrict__ sn,
    const int* __restrict__ slots,
    short* __restrict__ Qb, short* __restrict__ Kb, short* __restrict__ Vrow,
    float* __restrict__ kc, float* __restrict__ vc,
    int M, int N, int K) {
  __shared__ alignas(16) short Al[128 * 64];
  __shared__ alignas(16) short Bl[128 * 64];
  const int tid = threadIdx.x;
  const int wid = tid >> 6, lane = tid & 63;
  const int wr = wid >> 1, wc = wid & 1;
  const int l15 = lane & 15, lg = lane >> 4;
  const int gx = gridDim.x;
  const int id = blockIdx.y * gx + blockIdx.x;
  const int nwg = gx * gridDim.y;
  const int swz = (id & 7) * (nwg >> 3) + (id >> 3);
  const int row0 = (swz / gx) * 128, col0 = (swz % gx) * 128;
  const int lr8 = lane >> 3, l7 = lane & 7;

  f32x4 acc[4][4];
#pragma unroll
  for (int i = 0; i < 4; i++)
#pragma unroll
    for (int j = 0; j < 4; j++) acc[i][j] = {0.f, 0.f, 0.f, 0.f};

  for (int kt = 0; kt < K; kt += 64) {
#pragma unroll
    for (int c = 0; c < 4; c++) {
      int chunk = c * 4 + wid;
      int r = chunk * 8 + lr8;
      int ke = (l7 * 8) ^ ((r & 7) * 8);
      GLDS(A + (size_t)(row0 + r) * K + kt + ke, Al + chunk * 512);
      GLDS(Bt + (size_t)(col0 + r) * K + kt + ke, Bl + chunk * 512);
    }
    __syncthreads();
#pragma unroll
    for (int kk = 0; kk < 2; kk++) {
      frag16 af[4], bfv[4];
#pragma unroll
      for (int ai = 0; ai < 4; ai++) {
        int r = wr * 64 + ai * 16 + l15;
        int k0 = kk * 32 + lg * 8;
        af[ai] = *(const frag16*)(Al + r * 64 + (k0 ^ ((r & 7) * 8)));
      }
#pragma unroll
      for (int bj = 0; bj < 4; bj++) {
        int r = wc * 16 + (bj & 1) * 32 + ((bj >> 1) << 6) + l15;
        int k0 = kk * 32 + lg * 8;
        bfv[bj] = *(const frag16*)(Bl + r * 64 + (k0 ^ ((r & 7) * 8)));
      }
#pragma unroll
      for (int ai = 0; ai < 4; ai++)
#pragma unroll
        for (int bj = 0; bj < 4; bj++)
          acc[ai][bj] = __builtin_amdgcn_mfma_f32_16x16x32_bf16(
              af[ai], bfv[bj], acc[ai][bj], 0, 0, 0);
    }
    __syncthreads();
  }

  if (EPI == 0) {
#pragma unroll
    for (int ai = 0; ai < 4; ai++) {
#pragma unroll
      for (int bj = 0; bj < 4; bj++) {
        int row = row0 + wr * 64 + ai * 16 + lg * 4;
        int col = col0 + wc * 16 + (bj & 1) * 32 + ((bj >> 1) << 6) + l15;
#pragma unroll
        for (int r = 0; r < 4; r++)
          Cout[(size_t)(row + r) * N + col] = acc[ai][bj][r];
      }
    }
  } else {
    const int sec = col0 >> 11;            // 0=Q 1=K 2=V (uniform per block)
    const int h = (col0 & 2047) >> 7;
#pragma unroll
    for (int ai = 0; ai < 4; ai++) {
#pragma unroll
      for (int bj = 0; bj < 2; bj++) {
        const int d1 = wc * 16 + bj * 32 + l15;   // 0..63
        const float b1 = bias[col0 + d1];
        const float b2 = bias[col0 + d1 + 64];
        const int base = h * 128 + d1;
#pragma unroll
        for (int r = 0; r < 4; r++) {
          const int tok = row0 + wr * 64 + ai * 16 + lg * 4 + r;
          float v1 = acc[ai][bj][r] + b1;
          float v2 = acc[ai][bj + 2][r] + b2;
          if (sec == 0) {
            float c = cs[tok * 64 + d1], s = sn[tok * 64 + d1];
            Qb[(size_t)tok * HID + base]      = f2bf((v1 * c - v2 * s) * SCL);
            Qb[(size_t)tok * HID + base + 64] = f2bf((v2 * c + v1 * s) * SCL);
          } else if (sec == 1) {
            float c = cs[tok * 64 + d1], s = sn[tok * 64 + d1];
            float o1 = v1 * c - v2 * s, o2 = v2 * c + v1 * s;
            int sl = slots[tok];
            Kb[(size_t)tok * HID + base]      = f2bf(o1);
            Kb[(size_t)tok * HID + base + 64] = f2bf(o2);
            kc[(size_t)sl * HID + base]      = o1;
            kc[(size_t)sl * HID + base + 64] = o2;
          } else {
            int sl = slots[tok];
            vc[(size_t)sl * HID + base]      = v1;
            vc[(size_t)sl * HID + base + 64] = v2;
            Vrow[(size_t)tok * HID + base]      = f2bf(v1);
            Vrow[(size_t)tok * HID + base + 64] = f2bf(v2);
          }
        }
      }
    }
  }
}

// ---------------- causal flash attention v9: shared K/V fragments ------------
// Merged strip pairs (H=31-p, L=p) + register-direct P + defer-max +
// counted-vmcnt double-buffer (all from v7). NEW: tile-level proc loads each
// K-frag and V-frag ONCE and feeds both strips' MFMA chains (doL uniform)
// -> halves LDS b128 issue (the largest throughput term) on shared tiles.
__global__ __launch_bounds__(256, 2) void flash_attn9(
    const short* __restrict__ Qb, const short* __restrict__ Kb,
    const short* __restrict__ Vt, short* __restrict__ attn) {
  __shared__ alignas(16) short Klds[2][64 * 128];
  __shared__ alignas(16) short Vlds[2][128 * 64];

  const int tid = threadIdx.x;
  const int w = tid >> 6, lane = tid & 63;
  const int l15 = lane & 15, lg = lane >> 4;
  const int bid = blockIdx.x;
  const int p = bid >> 5;                  // 0..15: pair (31-p, p)
  const int bh = bid & 31;
  const int b = bh >> 4, h = bh & 15;

  frag16 ones;
#pragma unroll
  for (int q = 0; q < 8; q++) ones[q] = (short)0x3F80;

  auto stage = [&](int kv0, int buf) {     // 8 global_load_lds per thread
#pragma unroll
    for (int ci = 0; ci < 4; ci++) {
      int cc = w * 4 + ci;
      int krow = cc * 4 + (lane >> 4);
      int kss = (lane & 15) ^ (krow & 15);
      GLDS(Kb + (size_t)(b * SEQ + kv0 + krow) * HID + h * HD + kss * 8,
           Klds[buf] + cc * 512);
      int vd = cc * 8 + (lane >> 3);
      int vss = (lane & 7) ^ (vd & 7);
      GLDS(Vt + (size_t)(h * HD + vd) * TT + b * SEQ + kv0 + vss * 8,
           Vlds[buf] + cc * 512);
    }
  };

  const int qrowH = (31 - p) * 64 + w * 16;
  const int qrowL = p * 64 + w * 16;
  const int ntH = 32 - p;

  frag16 qfH[4], qfL[4];
  {
    const short* qpH = Qb + (size_t)(b * SEQ + qrowH + l15) * HID + h * HD + lg * 8;
    const short* qpL = Qb + (size_t)(b * SEQ + qrowL + l15) * HID + h * HD + lg * 8;
#pragma unroll
    for (int ds = 0; ds < 4; ds++) {
      qfH[ds] = *(const frag16*)(qpH + ds * 32);
      qfL[ds] = *(const frag16*)(qpL + ds * 32);
    }
  }
  f32x4 oH[8], oL[8];
#pragma unroll
  for (int q = 0; q < 8; q++) { oH[q] = {0.f, 0.f, 0.f, 0.f}; oL[q] = {0.f, 0.f, 0.f, 0.f}; }
  f32x4 laH = {0.f, 0.f, 0.f, 0.f}, laL = {0.f, 0.f, 0.f, 0.f};
  float mrH = -1e30f, mrL = -1e30f;

  // softmax on one strip's scores -> register-direct P fragments
  auto softmax = [&](f32x4 (&sa)[4], f32x4 (&o)[8], f32x4& la, float& mr,
                     bool diag, frag16& pf0, frag16& pf1) {
    if (diag) {
      int ql = 16 * w + l15;
#pragma unroll
      for (int f = 0; f < 4; f++)
#pragma unroll
        for (int r = 0; r < 4; r++)
          if (f * 16 + lg * 4 + r > ql) sa[f][r] = -1e30f;
    }
    float pm = sa[0][0];
#pragma unroll
    for (int f = 0; f < 4; f++)
#pragma unroll
      for (int r = 0; r < 4; r++) pm = fmaxf(pm, sa[f][r]);
    pm = fmaxf(pm, __shfl_xor(pm, 16));
    pm = fmaxf(pm, __shfl_xor(pm, 32));
    if (__any(pm > mr + 8.f)) {
      float mn = fmaxf(mr, pm);
      float frl = exp2f(mr - mn);
      mr = mn;
      float fr4[4];
#pragma unroll
      for (int r = 0; r < 4; r++)
        fr4[r] = __shfl(frl, lg * 16 + lg * 4 + r);
#pragma unroll
      for (int r = 0; r < 4; r++) {
        la[r] *= fr4[r];
#pragma unroll
        for (int q = 0; q < 8; q++) o[q][r] *= fr4[r];
      }
    }
    float pe[4][4];
#pragma unroll
    for (int f = 0; f < 4; f++)
#pragma unroll
      for (int r = 0; r < 4; r++) pe[f][r] = exp2f(sa[f][r] - mr);
    u32x4 w0, w1;
    w0[0] = cvtpk(pe[0][0], pe[0][1]); w0[1] = cvtpk(pe[0][2], pe[0][3]);
    w0[2] = cvtpk(pe[1][0], pe[1][1]); w0[3] = cvtpk(pe[1][2], pe[1][3]);
    w1[0] = cvtpk(pe[2][0], pe[2][1]); w1[1] = cvtpk(pe[2][2], pe[2][3]);
    w1[2] = cvtpk(pe[3][0], pe[3][1]); w1[3] = cvtpk(pe[3][2], pe[3][3]);
    pf0 = __builtin_bit_cast(frag16, w0);
    pf1 = __builtin_bit_cast(frag16, w1);
  };

  // tile-level proc: one pass over K/V frags feeding both strips
  auto tile_proc = [&](const short* Kl, const short* Vl, bool doL,
                       bool diagH, bool diagL) {
    f32x4 saH[4], saL[4];
#pragma unroll
    for (int f = 0; f < 4; f++) { saH[f] = {0.f, 0.f, 0.f, 0.f}; saL[f] = {0.f, 0.f, 0.f, 0.f}; }
    __builtin_amdgcn_s_setprio(1);
#pragma unroll
    for (int ds = 0; ds < 4; ds++) {
      int phys = (ds * 4 + lg) ^ l15;
#pragma unroll
      for (int f = 0; f < 4; f++) {
        frag16 kf = *(const frag16*)(Kl + (f * 16 + l15) * 128 + phys * 8);
        saH[f] = __builtin_amdgcn_mfma_f32_16x16x32_bf16(kf, qfH[ds], saH[f], 0, 0, 0);
        if (doL)
          saL[f] = __builtin_amdgcn_mfma_f32_16x16x32_bf16(kf, qfL[ds], saL[f], 0, 0, 0);
      }
    }
    __builtin_amdgcn_s_setprio(0);
    frag16 pfH0, pfH1, pfL0, pfL1;
    softmax(saH, oH, laH, mrH, diagH, pfH0, pfH1);
    if (doL) softmax(saL, oL, laL, mrL, diagL, pfL0, pfL1);
    __builtin_amdgcn_s_setprio(1);
    laH = __builtin_amdgcn_mfma_f32_16x16x32_bf16(pfH0, ones, laH, 0, 0, 0);
    laH = __builtin_amdgcn_mfma_f32_16x16x32_bf16(pfH1, ones, laH, 0, 0, 0);
    if (doL) {
      laL = __builtin_amdgcn_mfma_f32_16x16x32_bf16(pfL0, ones, laL, 0, 0, 0);
      laL = __builtin_amdgcn_mfma_f32_16x16x32_bf16(pfL1, ones, laL, 0, 0, 0);
    }
#pragma unroll
    for (int q = 0; q < 8; q++) {
      int d = q * 16 + l15;
      int p0 = lg ^ (d & 7);
      int p1 = (4 + lg) ^ (d & 7);
      frag16 vf0 = *(const frag16*)(Vl + d * 64 + p0 * 8);
      frag16 vf1 = *(const frag16*)(Vl + d * 64 + p1 * 8);
      oH[q] = __builtin_amdgcn_mfma_f32_16x16x32_bf16(pfH0, vf0, oH[q], 0, 0, 0);
      oH[q] = __builtin_amdgcn_mfma_f32_16x16x32_bf16(pfH1, vf1, oH[q], 0, 0, 0);
      if (doL) {
        oL[q] = __builtin_amdgcn_mfma_f32_16x16x32_bf16(pfL0, vf0, oL[q], 0, 0, 0);
        oL[q] = __builtin_amdgcn_mfma_f32_16x16x32_bf16(pfL1, vf1, oL[q], 0, 0, 0);
      }
    }
    __builtin_amdgcn_s_setprio(0);
  };

  stage(0, 0);
  if (ntH > 1) stage(64, 1);

  int cur = 0;
  for (int t = 0; t < ntH; t++) {
    if (t + 1 < ntH) {
      asm volatile("s_waitcnt vmcnt(8)" ::: "memory");   // tile t landed; t+1 in flight
    } else {
      asm volatile("s_waitcnt vmcnt(0)" ::: "memory");
    }
    asm volatile("s_barrier" ::: "memory");
    tile_proc(&Klds[cur][0], &Vlds[cur][0], t <= p, t == ntH - 1, t == p);
    asm volatile("s_barrier" ::: "memory");              // all waves done with buf cur
    if (t + 2 < ntH) stage((t + 2) * 64, cur);           // refill the freed buffer
    cur ^= 1;
  }

  {
    float inv[4];
#pragma unroll
    for (int r = 0; r < 4; r++) inv[r] = 1.f / laH[r];
    short* op = attn + (size_t)(b * SEQ + qrowH + lg * 4) * HID + h * HD + l15;
#pragma unroll
    for (int q = 0; q < 8; q++)
#pragma unroll
      for (int r = 0; r < 4; r++)
        op[(size_t)r * HID + q * 16] = f2bf(oH[q][r] * inv[r]);
  }
  {
    float inv[4];
#pragma unroll
    for (int r = 0; r < 4; r++) inv[r] = 1.f / laL[r];
    short* op = attn + (size_t)(b * SEQ + qrowL + lg * 4) * HID + h * HD + l15;
#pragma unroll
    for (int q = 0; q < 8; q++)
#pragma unroll
      for (int r = 0; r < 4; r++)
        op[(size_t)r * HID + q * 16] = f2bf(oL[q][r] * inv[r]);
  }
}

// ---------------- launcher ----------------
extern "C" void kernel_launch(void* const* d_in, const int* in_sizes, int n_in,
                              void* d_out, int out_size, void* d_ws, size_t ws_size,
                              hipStream_t stream) {
  const float* hidden = (const float*)d_in[0];
  const float* cosb   = (const float*)d_in[1];
  const float* sinb   = (const float*)d_in[2];
  const float* wqkv   = (const float*)d_in[3];
  const float* bqkv   = (const float*)d_in[4];
  const float* wo     = (const float*)d_in[5];
  const int*   slots  = (const int*)d_in[9];

  float* out = (float*)d_out;
  float* kc  = out + (size_t)TT * HID;
  float* vc  = kc + (size_t)TT * HID;

  short* ws    = (short*)d_ws;
  short* Abf   = ws;                       // 8,388,608 shorts (reused as attnb)
  short* Wqkvt = Abf + 8388608;            // 12,582,912
  short* Wot   = Wqkvt + 12582912;         // 4,194,304
  short* Qb    = Wot + 4194304;            // 8,388,608
  short* Kb    = Qb + 8388608;             // 8,388,608
  short* Vrow  = Kb + 8388608;             // 8,388,608
  short* Vt    = Vrow + 8388608;           // 8,388,608
  short* attnb = Abf;                      // reuse (A dead after GEMM1)

  prep<<<8192 + 3072 + 1024, 256, 0, stream>>>(hidden, Abf, wqkv, Wqkvt, wo, Wot);
  gemm_bt<1><<<dim3(48, 32), 256, 0, stream>>>(
      Abf, Wqkvt, bqkv, nullptr, cosb, sinb, slots, Qb, Kb, Vrow, kc, vc,
      TT, NQKV, HID);
  transpose_perm<<<dim3(32, 64), 256, 0, stream>>>(Vrow, Vt, HID, TT);
  flash_attn9<<<512, 256, 0, stream>>>(Qb, Kb, Vt, attnb);
  gemm_bt<0><<<dim3(16, 32), 256, 0, stream>>>(
      attnb, Wot, nullptr, out, nullptr, nullptr, nullptr,
      nullptr, nullptr, nullptr, nullptr, nullptr, TT, HID, HID);
}

// Round 13
// 289.679 us; speedup vs baseline: 1.0386x; 1.0386x over previous
//
#include <hip/hip_runtime.h>

using f32x4  = __attribute__((ext_vector_type(4))) float;
using frag16 = __attribute__((ext_vector_type(8))) short;
using s16x4  = __attribute__((ext_vector_type(4))) short;
using s16x8  = __attribute__((ext_vector_type(8))) short;
using u32x4  = __attribute__((ext_vector_type(4))) unsigned;

#define DI __device__ __forceinline__

constexpr int HID  = 2048;
constexpr int NH   = 16;
constexpr int HD   = 128;
constexpr int TT   = 4096;   // total tokens
constexpr int SEQ  = 2048;
constexpr int NQKV = 3 * HID; // 6144
constexpr float SCL = 0.08838834764831845f * 1.4426950408889634f; // scale*log2e

DI short f2bf(float f) {
  unsigned u = __builtin_bit_cast(unsigned, f);
  unsigned r = (u + 0x7fffu + ((u >> 16) & 1u)) >> 16;
  return (short)r;
}
DI float bf2f(short s) {
  unsigned u = ((unsigned)(unsigned short)s) << 16;
  return __builtin_bit_cast(float, u);
}
DI unsigned cvtpk(float lo, float hi) {
  unsigned r;
  asm("v_cvt_pk_bf16_f32 %0, %1, %2" : "=v"(r) : "v"(lo), "v"(hi));
  return r;
}

// ---------------- elementwise f32 -> bf16 ----------------
struct alignas(8) S4h { short a, b, c, d; };

__global__ void conv_f32_bf16(const float* __restrict__ in, short* __restrict__ out) {
  int gid = blockIdx.x * 256 + threadIdx.x;
  const float4* in4 = (const float4*)in;
  float4 v = in4[gid];
  S4h o{f2bf(v.x), f2bf(v.y), f2bf(v.z), f2bf(v.w)};
  ((S4h*)out)[gid] = o;
}

// ---------------- transpose (+convert) : out[c][r] = in[r][c] ----------------
// PERM (for attention register-P token order): dest col c holds source token
// t(c) = (c>>5)*32 + ((c>>2)&1)*16 + ((c>>3)&3)*4 + (c&3)   (bit permutation)
template <bool IN_F32, bool PERM>
__global__ void transpose_conv(const void* __restrict__ in_, short* __restrict__ out,
                               int ldin, int R) {
  __shared__ float t[64][65];
  const float* inf = (const float*)in_;
  const short* ins = (const short*)in_;
  int tid = threadIdx.x;
  int bx = blockIdx.x, by = blockIdx.y;
#pragma unroll
  for (int i = 0; i < 4; i++) {
    int idx = i * 256 + tid;
    int r = idx >> 4, c4 = idx & 15;
    size_t gi = (size_t)(by * 64 + r) * ldin + bx * 64 + c4 * 4;
    if (IN_F32) {
      float4 v = *(const float4*)(inf + gi);
      t[r][c4 * 4] = v.x; t[r][c4 * 4 + 1] = v.y;
      t[r][c4 * 4 + 2] = v.z; t[r][c4 * 4 + 3] = v.w;
    } else {
      s16x4 v = *(const s16x4*)(ins + gi);
#pragma unroll
      for (int j = 0; j < 4; j++) t[r][c4 * 4 + j] = bf2f(v[j]);
    }
  }
  __syncthreads();
#pragma unroll
  for (int i = 0; i < 4; i++) {
    int idx = i * 256 + tid;
    int r = idx >> 4, c4 = idx & 15;
    s16x4 o;
#pragma unroll
    for (int j = 0; j < 4; j++) {
      int c = c4 * 4 + j;
      int cs = PERM ? ((c >> 5) * 32 + ((c >> 2) & 1) * 16 + ((c >> 3) & 3) * 4 + (c & 3))
                    : c;
      o[j] = f2bf(t[cs][r]);
    }
    *(s16x4*)(out + (size_t)(bx * 64 + r) * R + by * 64 + c4 * 4) = o;
  }
}

#define GLDS(src, dst)                                                     \
  __builtin_amdgcn_global_load_lds(                                        \
      (const __attribute__((address_space(1))) void*)(src),                \
      (__attribute__((address_space(3))) void*)(dst), 16, 0, 0)

// ---------------- bf16 MFMA GEMM, B transposed (N x K), 128x128 tile ----------
// Wave cols remapped to {0,32,64,96}+wc*16 so (d, d+64) pairs are lane-local.
// EPI=0: plain f32 out. EPI=1: fused bias+RoPE epilogue for the QKV projection:
// writes Qb (rope'd, pre-scaled), Kb+kc (rope'd), vc, and row-major Vrow (bf16).
template <int EPI>
__global__ __launch_bounds__(256, 2) void gemm_bt(
    const short* __restrict__ A, const short* __restrict__ Bt,
    const float* __restrict__ bias, float* __restrict__ Cout,
    const float* __restrict__ cs, const float* __restrict__ sn,
    const int* __restrict__ slots,
    short* __restrict__ Qb, short* __restrict__ Kb, short* __restrict__ Vrow,
    float* __restrict__ kc, float* __restrict__ vc,
    int M, int N, int K) {
  __shared__ alignas(16) short Al[128 * 64];
  __shared__ alignas(16) short Bl[128 * 64];
  const int tid = threadIdx.x;
  const int wid = tid >> 6, lane = tid & 63;
  const int wr = wid >> 1, wc = wid & 1;
  const int l15 = lane & 15, lg = lane >> 4;
  // XCD-aware swizzle (grid counts are multiples of 8)
  const int gx = gridDim.x;
  const int id = blockIdx.y * gx + blockIdx.x;
  const int nwg = gx * gridDim.y;
  const int swz = (id & 7) * (nwg >> 3) + (id >> 3);
  const int row0 = (swz / gx) * 128, col0 = (swz % gx) * 128;
  const int lr8 = lane >> 3, l7 = lane & 7;

  f32x4 acc[4][4];
#pragma unroll
  for (int i = 0; i < 4; i++)
#pragma unroll
    for (int j = 0; j < 4; j++) acc[i][j] = {0.f, 0.f, 0.f, 0.f};

  for (int kt = 0; kt < K; kt += 64) {
#pragma unroll
    for (int c = 0; c < 4; c++) {
      int chunk = c * 4 + wid;             // 0..15 (1KB chunks)
      int r = chunk * 8 + lr8;             // LDS row 0..127
      int ke = (l7 * 8) ^ ((r & 7) * 8);   // element offset within 64-wide row
      GLDS(A + (size_t)(row0 + r) * K + kt + ke, Al + chunk * 512);
      GLDS(Bt + (size_t)(col0 + r) * K + kt + ke, Bl + chunk * 512);
    }
    __syncthreads();
#pragma unroll
    for (int kk = 0; kk < 2; kk++) {
      frag16 af[4], bfv[4];
#pragma unroll
      for (int ai = 0; ai < 4; ai++) {
        int r = wr * 64 + ai * 16 + l15;
        int k0 = kk * 32 + lg * 8;
        af[ai] = *(const frag16*)(Al + r * 64 + (k0 ^ ((r & 7) * 8)));
      }
#pragma unroll
      for (int bj = 0; bj < 4; bj++) {
        int r = wc * 16 + (bj & 1) * 32 + ((bj >> 1) << 6) + l15;
        int k0 = kk * 32 + lg * 8;
        bfv[bj] = *(const frag16*)(Bl + r * 64 + (k0 ^ ((r & 7) * 8)));
      }
#pragma unroll
      for (int ai = 0; ai < 4; ai++)
#pragma unroll
        for (int bj = 0; bj < 4; bj++)
          acc[ai][bj] = __builtin_amdgcn_mfma_f32_16x16x32_bf16(
              af[ai], bfv[bj], acc[ai][bj], 0, 0, 0);
    }
    __syncthreads();
  }

  if (EPI == 0) {
#pragma unroll
    for (int ai = 0; ai < 4; ai++) {
#pragma unroll
      for (int bj = 0; bj < 4; bj++) {
        int row = row0 + wr * 64 + ai * 16 + lg * 4;
        int col = col0 + wc * 16 + (bj & 1) * 32 + ((bj >> 1) << 6) + l15;
#pragma unroll
        for (int r = 0; r < 4; r++)
          Cout[(size_t)(row + r) * N + col] = acc[ai][bj][r];
      }
    }
  } else {
    const int sec = col0 >> 11;            // 0=Q 1=K 2=V (uniform per block)
    const int h = (col0 & 2047) >> 7;
#pragma unroll
    for (int ai = 0; ai < 4; ai++) {
#pragma unroll
      for (int bj = 0; bj < 2; bj++) {
        const int d1 = wc * 16 + bj * 32 + l15;   // 0..63
        const float b1 = bias[col0 + d1];
        const float b2 = bias[col0 + d1 + 64];
        const int base = h * 128 + d1;
#pragma unroll
        for (int r = 0; r < 4; r++) {
          const int tok = row0 + wr * 64 + ai * 16 + lg * 4 + r;
          float v1 = acc[ai][bj][r] + b1;
          float v2 = acc[ai][bj + 2][r] + b2;
          if (sec == 0) {
            float c = cs[tok * 64 + d1], s = sn[tok * 64 + d1];
            Qb[(size_t)tok * HID + base]      = f2bf((v1 * c - v2 * s) * SCL);
            Qb[(size_t)tok * HID + base + 64] = f2bf((v2 * c + v1 * s) * SCL);
          } else if (sec == 1) {
            float c = cs[tok * 64 + d1], s = sn[tok * 64 + d1];
            float o1 = v1 * c - v2 * s, o2 = v2 * c + v1 * s;
            int sl = slots[tok];
            Kb[(size_t)tok * HID + base]      = f2bf(o1);
            Kb[(size_t)tok * HID + base + 64] = f2bf(o2);
            kc[(size_t)sl * HID + base]      = o1;
            kc[(size_t)sl * HID + base + 64] = o2;
          } else {
            int sl = slots[tok];
            vc[(size_t)sl * HID + base]      = v1;
            vc[(size_t)sl * HID + base + 64] = v2;
            Vrow[(size_t)tok * HID + base]      = f2bf(v1);
            Vrow[(size_t)tok * HID + base + 64] = f2bf(v2);
          }
        }
      }
    }
  }
}

// ---------------- causal flash attention v6: register-direct P ----------------
// Merged strip pairs (H=31-p, L=p share staged K/V prefix). Swapped QK^T puts
// P's q-row on l15 = exactly the PV A-operand's m=l15; lane's 16 in-register
// values fill A-slots k=lg*8+j / 32+lg*8+j under the token bit-perm baked
// into Vt -> P never touches LDS (8 cvt_pk -> two frag16).
__global__ __launch_bounds__(256, 2) void flash_attn6(
    const short* __restrict__ Qb, const short* __restrict__ Kb,
    const short* __restrict__ Vt, short* __restrict__ attn) {
  __shared__ alignas(16) short Klds[2][64 * 128];
  __shared__ alignas(16) short Vlds[2][128 * 64];

  const int tid = threadIdx.x;
  const int w = tid >> 6, lane = tid & 63;
  const int l15 = lane & 15, lg = lane >> 4;
  const int bid = blockIdx.x;
  const int p = bid >> 5;                  // 0..15: pair (31-p, p)
  const int bh = bid & 31;
  const int b = bh >> 4, h = bh & 15;

  frag16 ones;
#pragma unroll
  for (int j = 0; j < 8; j++) ones[j] = (short)0x3F80;

  auto stage = [&](int kv0, int buf) {
#pragma unroll
    for (int ci = 0; ci < 4; ci++) {
      int cc = w * 4 + ci;                 // 0..15
      int krow = cc * 4 + (lane >> 4);
      int kss = (lane & 15) ^ (krow & 15);
      GLDS(Kb + (size_t)(b * SEQ + kv0 + krow) * HID + h * HD + kss * 8,
           Klds[buf] + cc * 512);
      int vd = cc * 8 + (lane >> 3);
      int vss = (lane & 7) ^ (vd & 7);
      GLDS(Vt + (size_t)(h * HD + vd) * TT + b * SEQ + kv0 + vss * 8,
           Vlds[buf] + cc * 512);
    }
  };

  const int qrowH = (31 - p) * 64 + w * 16;
  const int qrowL = p * 64 + w * 16;
  const int ntH = 32 - p;                  // tiles for heavy strip

  frag16 qfH[4], qfL[4];
  {
    const short* qpH = Qb + (size_t)(b * SEQ + qrowH + l15) * HID + h * HD + lg * 8;
    const short* qpL = Qb + (size_t)(b * SEQ + qrowL + l15) * HID + h * HD + lg * 8;
#pragma unroll
    for (int ds = 0; ds < 4; ds++) {
      qfH[ds] = *(const frag16*)(qpH + ds * 32);
      qfL[ds] = *(const frag16*)(qpL + ds * 32);
    }
  }
  f32x4 oH[8], oL[8];
#pragma unroll
  for (int j = 0; j < 8; j++) { oH[j] = {0.f, 0.f, 0.f, 0.f}; oL[j] = {0.f, 0.f, 0.f, 0.f}; }
  f32x4 laH = {0.f, 0.f, 0.f, 0.f}, laL = {0.f, 0.f, 0.f, 0.f};
  float mrH = -1e30f, mrL = -1e30f;

  auto proc = [&](const frag16 (&qf)[4], f32x4 (&o)[8], f32x4& la, float& mr,
                  bool diag, const short* Kl, const short* Vl) {
    f32x4 sa[4];
#pragma unroll
    for (int f = 0; f < 4; f++) sa[f] = {0.f, 0.f, 0.f, 0.f};
    __builtin_amdgcn_s_setprio(1);
#pragma unroll
    for (int ds = 0; ds < 4; ds++) {
      int phys = (ds * 4 + lg) ^ l15;
#pragma unroll
      for (int f = 0; f < 4; f++) {
        frag16 kf = *(const frag16*)(Kl + (f * 16 + l15) * 128 + phys * 8);
        sa[f] = __builtin_amdgcn_mfma_f32_16x16x32_bf16(kf, qf[ds], sa[f], 0, 0, 0);
      }
    }
    __builtin_amdgcn_s_setprio(0);
    if (diag) {
      int ql = 16 * w + l15;
#pragma unroll
      for (int f = 0; f < 4; f++)
#pragma unroll
        for (int r = 0; r < 4; r++)
          if (f * 16 + lg * 4 + r > ql) sa[f][r] = -1e30f;
    }
    float pm = sa[0][0];
#pragma unroll
    for (int f = 0; f < 4; f++)
#pragma unroll
      for (int r = 0; r < 4; r++) pm = fmaxf(pm, sa[f][r]);
    pm = fmaxf(pm, __shfl_xor(pm, 16));
    pm = fmaxf(pm, __shfl_xor(pm, 32));
    if (__any(pm > mr + 8.f)) {
      float mn = fmaxf(mr, pm);
      float frl = exp2f(mr - mn);
      mr = mn;
      float fr4[4];
#pragma unroll
      for (int r = 0; r < 4; r++)
        fr4[r] = __shfl(frl, lg * 16 + lg * 4 + r);
#pragma unroll
      for (int r = 0; r < 4; r++) {
        la[r] *= fr4[r];
#pragma unroll
        for (int j = 0; j < 8; j++) o[j][r] *= fr4[r];
      }
    }
    float pe[4][4];
#pragma unroll
    for (int f = 0; f < 4; f++)
#pragma unroll
      for (int r = 0; r < 4; r++) pe[f][r] = exp2f(sa[f][r] - mr);
    // register-direct P: pf0 shorts j = pe[j>>2][j&3], pf1 = pe[2+(j>>2)][j&3]
    u32x4 w0, w1;
    w0[0] = cvtpk(pe[0][0], pe[0][1]); w0[1] = cvtpk(pe[0][2], pe[0][3]);
    w0[2] = cvtpk(pe[1][0], pe[1][1]); w0[3] = cvtpk(pe[1][2], pe[1][3]);
    w1[0] = cvtpk(pe[2][0], pe[2][1]); w1[1] = cvtpk(pe[2][2], pe[2][3]);
    w1[2] = cvtpk(pe[3][0], pe[3][1]); w1[3] = cvtpk(pe[3][2], pe[3][3]);
    frag16 pf0 = __builtin_bit_cast(frag16, w0);
    frag16 pf1 = __builtin_bit_cast(frag16, w1);
    __builtin_amdgcn_s_setprio(1);
    la = __builtin_amdgcn_mfma_f32_16x16x32_bf16(pf0, ones, la, 0, 0, 0);
    la = __builtin_amdgcn_mfma_f32_16x16x32_bf16(pf1, ones, la, 0, 0, 0);
#pragma unroll
    for (int j = 0; j < 8; j++) {
      int d = j * 16 + l15;
      int p0 = lg ^ (d & 7);
      int p1 = (4 + lg) ^ (d & 7);
      frag16 vf0 = *(const frag16*)(Vl + d * 64 + p0 * 8);
      frag16 vf1 = *(const frag16*)(Vl + d * 64 + p1 * 8);
      o[j] = __builtin_amdgcn_mfma_f32_16x16x32_bf16(pf0, vf0, o[j], 0, 0, 0);
      o[j] = __builtin_amdgcn_mfma_f32_16x16x32_bf16(pf1, vf1, o[j], 0, 0, 0);
    }
    __builtin_amdgcn_s_setprio(0);
  };

  stage(0, 0);
  __syncthreads();

  int cur = 0;
  for (int t = 0; t < ntH; t++) {
    if (t + 1 < ntH) stage((t + 1) * 64, cur ^ 1);
    const short* Kl = &Klds[cur][0];
    const short* Vl = &Vlds[cur][0];
    proc(qfH, oH, laH, mrH, t == ntH - 1, Kl, Vl);
    if (t <= p) proc(qfL, oL, laL, mrL, t == p, Kl, Vl);
    __syncthreads();
    cur ^= 1;
  }

  {
    float inv[4];
#pragma unroll
    for (int r = 0; r < 4; r++) inv[r] = 1.f / laH[r];
    short* op = attn + (size_t)(b * SEQ + qrowH + lg * 4) * HID + h * HD + l15;
#pragma unroll
    for (int j = 0; j < 8; j++)
#pragma unroll
      for (int r = 0; r < 4; r++)
        op[(size_t)r * HID + j * 16] = f2bf(oH[j][r] * inv[r]);
  }
  {
    float inv[4];
#pragma unroll
    for (int r = 0; r < 4; r++) inv[r] = 1.f / laL[r];
    short* op = attn + (size_t)(b * SEQ + qrowL + lg * 4) * HID + h * HD + l15;
#pragma unroll
    for (int j = 0; j < 8; j++)
#pragma unroll
      for (int r = 0; r < 4; r++)
        op[(size_t)r * HID + j * 16] = f2bf(oL[j][r] * inv[r]);
  }
}

// ---------------- launcher ----------------
extern "C" void kernel_launch(void* const* d_in, const int* in_sizes, int n_in,
                              void* d_out, int out_size, void* d_ws, size_t ws_size,
                              hipStream_t stream) {
  const float* hidden = (const float*)d_in[0];
  const float* cosb   = (const float*)d_in[1];
  const float* sinb   = (const float*)d_in[2];
  const float* wqkv   = (const float*)d_in[3];
  const float* bqkv   = (const float*)d_in[4];
  const float* wo     = (const float*)d_in[5];
  const int*   slots  = (const int*)d_in[9];

  float* out = (float*)d_out;
  float* kc  = out + (size_t)TT * HID;
  float* vc  = kc + (size_t)TT * HID;

  short* ws    = (short*)d_ws;
  short* Abf   = ws;                       // 8,388,608 shorts (reused as attnb)
  short* Wqkvt = Abf + 8388608;            // 12,582,912
  short* Wot   = Wqkvt + 12582912;         // 4,194,304
  short* Qb    = Wot + 4194304;            // 8,388,608
  short* Kb    = Qb + 8388608;             // 8,388,608
  short* Vrow  = Kb + 8388608;             // 8,388,608
  short* Vt    = Vrow + 8388608;           // 8,388,608
  short* attnb = Abf;                      // reuse (A dead after GEMM1)

  conv_f32_bf16<<<8192, 256, 0, stream>>>(hidden, Abf);
  transpose_conv<true, false><<<dim3(96, 32), 256, 0, stream>>>(wqkv, Wqkvt, NQKV, HID);
  transpose_conv<true, false><<<dim3(32, 32), 256, 0, stream>>>(wo, Wot, HID, HID);
  gemm_bt<1><<<dim3(48, 32), 256, 0, stream>>>(
      Abf, Wqkvt, bqkv, nullptr, cosb, sinb, slots, Qb, Kb, Vrow, kc, vc,
      TT, NQKV, HID);
  transpose_conv<false, true><<<dim3(32, 64), 256, 0, stream>>>(Vrow, Vt, HID, TT);
  flash_attn6<<<512, 256, 0, stream>>>(Qb, Kb, Vt, attnb);
  gemm_bt<0><<<dim3(16, 32), 256, 0, stream>>>(
      attnb, Wot, nullptr, out, nullptr, nullptr, nullptr,
      nullptr, nullptr, nullptr, nullptr, nullptr, TT, HID, HID);
}

// Round 14
// 282.851 us; speedup vs baseline: 1.0637x; 1.0241x over previous
//
#include <hip/hip_runtime.h>

using f32x4  = __attribute__((ext_vector_type(4))) float;
using frag16 = __attribute__((ext_vector_type(8))) short;
using s16x4  = __attribute__((ext_vector_type(4))) short;
using s16x8  = __attribute__((ext_vector_type(8))) short;
using u32x4  = __attribute__((ext_vector_type(4))) unsigned;

#define DI __device__ __forceinline__

constexpr int HID  = 2048;
constexpr int NH   = 16;
constexpr int HD   = 128;
constexpr int TT   = 4096;   // total tokens
constexpr int SEQ  = 2048;
constexpr int NQKV = 3 * HID; // 6144
constexpr float SCL = 0.08838834764831845f * 1.4426950408889634f; // scale*log2e

DI short f2bf(float f) {
  unsigned u = __builtin_bit_cast(unsigned, f);
  unsigned r = (u + 0x7fffu + ((u >> 16) & 1u)) >> 16;
  return (short)r;
}
DI float bf2f(short s) {
  unsigned u = ((unsigned)(unsigned short)s) << 16;
  return __builtin_bit_cast(float, u);
}
DI unsigned cvtpk(float lo, float hi) {
  unsigned r;
  asm("v_cvt_pk_bf16_f32 %0, %1, %2" : "=v"(r) : "v"(lo), "v"(hi));
  return r;
}

// ---------------- merged prep: hidden conv + wqkv^T + wo^T (one launch) -----
struct alignas(8) S4h { short a, b, c, d; };

__global__ void prep(const float* __restrict__ hidden, short* __restrict__ Abf,
                     const float* __restrict__ wqkv, short* __restrict__ Wqkvt,
                     const float* __restrict__ wo, short* __restrict__ Wot) {
  __shared__ float t[64][65];
  const int bid = blockIdx.x;
  const int tid = threadIdx.x;
  if (bid < 8192) {                      // f32 -> bf16 convert of hidden
    int gid = bid * 256 + tid;
    float4 v = ((const float4*)hidden)[gid];
    S4h o{f2bf(v.x), f2bf(v.y), f2bf(v.z), f2bf(v.w)};
    ((S4h*)Abf)[gid] = o;
    return;
  }
  const float* in;
  short* out;
  int ldin, R, bx, by;
  if (bid < 8192 + 3072) {               // wqkv (2048 x 6144) -> (6144 x 2048)
    int idx = bid - 8192;
    in = wqkv; out = Wqkvt; ldin = NQKV; R = HID;
    bx = idx % 96; by = idx / 96;
  } else {                               // wo (2048 x 2048) -> (2048 x 2048)
    int idx = bid - 8192 - 3072;
    in = wo; out = Wot; ldin = HID; R = HID;
    bx = idx % 32; by = idx / 32;
  }
#pragma unroll
  for (int i = 0; i < 4; i++) {
    int idx = i * 256 + tid;
    int r = idx >> 4, c4 = idx & 15;
    size_t gi = (size_t)(by * 64 + r) * ldin + bx * 64 + c4 * 4;
    float4 v = *(const float4*)(in + gi);
    t[r][c4 * 4] = v.x; t[r][c4 * 4 + 1] = v.y;
    t[r][c4 * 4 + 2] = v.z; t[r][c4 * 4 + 3] = v.w;
  }
  __syncthreads();
#pragma unroll
  for (int i = 0; i < 4; i++) {
    int idx = i * 256 + tid;
    int r = idx >> 4, c4 = idx & 15;
    s16x4 o;
#pragma unroll
    for (int j = 0; j < 4; j++) o[j] = f2bf(t[c4 * 4 + j][r]);
    *(s16x4*)(out + (size_t)(bx * 64 + r) * R + by * 64 + c4 * 4) = o;
  }
}

// ---------------- post: Vt transpose (token bit-perm) + kc/vc cache scatter --
// blocks 0..2047: Vrow -> Vt transpose; dest col c holds source token
//   t(c) = (c>>5)*32 + ((c>>2)&1)*16 + ((c>>3)&3)*4 + (c&3)
// blocks 2048..6143: token-row copy Kb->kc, Vrow->vc (bf16 -> f32, slots scatter)
__global__ void post(const short* __restrict__ Kb, const short* __restrict__ Vrow,
                     short* __restrict__ Vt, const int* __restrict__ slots,
                     float* __restrict__ kc, float* __restrict__ vc) {
  __shared__ float t[64][65];
  const int bid = blockIdx.x;
  const int tid = threadIdx.x;
  if (bid < 2048) {
    int bx = bid & 31, by = bid >> 5;    // bx: HID/64, by: TT/64
#pragma unroll
    for (int i = 0; i < 4; i++) {
      int idx = i * 256 + tid;
      int r = idx >> 4, c4 = idx & 15;
      size_t gi = (size_t)(by * 64 + r) * HID + bx * 64 + c4 * 4;
      s16x4 v = *(const s16x4*)(Vrow + gi);
#pragma unroll
      for (int j = 0; j < 4; j++) t[r][c4 * 4 + j] = bf2f(v[j]);
    }
    __syncthreads();
#pragma unroll
    for (int i = 0; i < 4; i++) {
      int idx = i * 256 + tid;
      int r = idx >> 4, c4 = idx & 15;
      s16x4 o;
#pragma unroll
      for (int j = 0; j < 4; j++) {
        int c = c4 * 4 + j;
        int cs = (c >> 5) * 32 + ((c >> 2) & 1) * 16 + ((c >> 3) & 3) * 4 + (c & 3);
        o[j] = f2bf(t[cs][r]);
      }
      *(s16x4*)(Vt + (size_t)(bx * 64 + r) * TT + by * 64 + c4 * 4) = o;
    }
    return;
  }
  const int tok = bid - 2048;            // 0..4095
  const int slot = slots[tok];
  const short* kr = Kb + (size_t)tok * HID;
  const short* vr = Vrow + (size_t)tok * HID;
  float* kco = kc + (size_t)slot * HID;
  float* vco = vc + (size_t)slot * HID;
  const int i = tid * 8;
  s16x8 k8 = *(const s16x8*)(kr + i);
  s16x8 v8 = *(const s16x8*)(vr + i);
  *(float4*)(kco + i)     = {bf2f(k8[0]), bf2f(k8[1]), bf2f(k8[2]), bf2f(k8[3])};
  *(float4*)(kco + i + 4) = {bf2f(k8[4]), bf2f(k8[5]), bf2f(k8[6]), bf2f(k8[7])};
  *(float4*)(vco + i)     = {bf2f(v8[0]), bf2f(v8[1]), bf2f(v8[2]), bf2f(v8[3])};
  *(float4*)(vco + i + 4) = {bf2f(v8[4]), bf2f(v8[5]), bf2f(v8[6]), bf2f(v8[7])};
}

#define GLDS(src, dst)                                                     \
  __builtin_amdgcn_global_load_lds(                                        \
      (const __attribute__((address_space(1))) void*)(src),                \
      (__attribute__((address_space(3))) void*)(dst), 16, 0, 0)

// ---------------- bf16 MFMA GEMM, B transposed (N x K), 128x128 tile ----------
// Wave cols remapped to {0,32,64,96}+wc*16 so (d, d+64) pairs are lane-local.
// EPI=0: plain f32 out. EPI=1: fused bias+RoPE epilogue writing ONLY the bf16
// tensors (Qb rope'd+pre-scaled, Kb rope'd, Vrow); kc/vc moved to post kernel.
template <int EPI>
__global__ __launch_bounds__(256, 2) void gemm_bt(
    const short* __restrict__ A, const short* __restrict__ Bt,
    const float* __restrict__ bias, float* __restrict__ Cout,
    const float* __restrict__ cs, const float* __restrict__ sn,
    short* __restrict__ Qb, short* __restrict__ Kb, short* __restrict__ Vrow,
    int M, int N, int K) {
  __shared__ alignas(16) short Al[128 * 64];
  __shared__ alignas(16) short Bl[128 * 64];
  const int tid = threadIdx.x;
  const int wid = tid >> 6, lane = tid & 63;
  const int wr = wid >> 1, wc = wid & 1;
  const int l15 = lane & 15, lg = lane >> 4;
  // XCD-aware swizzle (grid counts are multiples of 8)
  const int gx = gridDim.x;
  const int id = blockIdx.y * gx + blockIdx.x;
  const int nwg = gx * gridDim.y;
  const int swz = (id & 7) * (nwg >> 3) + (id >> 3);
  const int row0 = (swz / gx) * 128, col0 = (swz % gx) * 128;
  const int lr8 = lane >> 3, l7 = lane & 7;

  f32x4 acc[4][4];
#pragma unroll
  for (int i = 0; i < 4; i++)
#pragma unroll
    for (int j = 0; j < 4; j++) acc[i][j] = {0.f, 0.f, 0.f, 0.f};

  for (int kt = 0; kt < K; kt += 64) {
#pragma unroll
    for (int c = 0; c < 4; c++) {
      int chunk = c * 4 + wid;             // 0..15 (1KB chunks)
      int r = chunk * 8 + lr8;             // LDS row 0..127
      int ke = (l7 * 8) ^ ((r & 7) * 8);   // element offset within 64-wide row
      GLDS(A + (size_t)(row0 + r) * K + kt + ke, Al + chunk * 512);
      GLDS(Bt + (size_t)(col0 + r) * K + kt + ke, Bl + chunk * 512);
    }
    __syncthreads();
#pragma unroll
    for (int kk = 0; kk < 2; kk++) {
      frag16 af[4], bfv[4];
#pragma unroll
      for (int ai = 0; ai < 4; ai++) {
        int r = wr * 64 + ai * 16 + l15;
        int k0 = kk * 32 + lg * 8;
        af[ai] = *(const frag16*)(Al + r * 64 + (k0 ^ ((r & 7) * 8)));
      }
#pragma unroll
      for (int bj = 0; bj < 4; bj++) {
        int r = wc * 16 + (bj & 1) * 32 + ((bj >> 1) << 6) + l15;
        int k0 = kk * 32 + lg * 8;
        bfv[bj] = *(const frag16*)(Bl + r * 64 + (k0 ^ ((r & 7) * 8)));
      }
#pragma unroll
      for (int ai = 0; ai < 4; ai++)
#pragma unroll
        for (int bj = 0; bj < 4; bj++)
          acc[ai][bj] = __builtin_amdgcn_mfma_f32_16x16x32_bf16(
              af[ai], bfv[bj], acc[ai][bj], 0, 0, 0);
    }
    __syncthreads();
  }

  if (EPI == 0) {
#pragma unroll
    for (int ai = 0; ai < 4; ai++) {
#pragma unroll
      for (int bj = 0; bj < 4; bj++) {
        int row = row0 + wr * 64 + ai * 16 + lg * 4;
        int col = col0 + wc * 16 + (bj & 1) * 32 + ((bj >> 1) << 6) + l15;
#pragma unroll
        for (int r = 0; r < 4; r++)
          Cout[(size_t)(row + r) * N + col] = acc[ai][bj][r];
      }
    }
  } else {
    const int sec = col0 >> 11;            // 0=Q 1=K 2=V (uniform per block)
    const int h = (col0 & 2047) >> 7;
#pragma unroll
    for (int ai = 0; ai < 4; ai++) {
#pragma unroll
      for (int bj = 0; bj < 2; bj++) {
        const int d1 = wc * 16 + bj * 32 + l15;   // 0..63
        const float b1 = bias[col0 + d1];
        const float b2 = bias[col0 + d1 + 64];
        const int base = h * 128 + d1;
#pragma unroll
        for (int r = 0; r < 4; r++) {
          const int tok = row0 + wr * 64 + ai * 16 + lg * 4 + r;
          float v1 = acc[ai][bj][r] + b1;
          float v2 = acc[ai][bj + 2][r] + b2;
          if (sec == 0) {
            float c = cs[tok * 64 + d1], s = sn[tok * 64 + d1];
            Qb[(size_t)tok * HID + base]      = f2bf((v1 * c - v2 * s) * SCL);
            Qb[(size_t)tok * HID + base + 64] = f2bf((v2 * c + v1 * s) * SCL);
          } else if (sec == 1) {
            float c = cs[tok * 64 + d1], s = sn[tok * 64 + d1];
            Kb[(size_t)tok * HID + base]      = f2bf(v1 * c - v2 * s);
            Kb[(size_t)tok * HID + base + 64] = f2bf(v2 * c + v1 * s);
          } else {
            Vrow[(size_t)tok * HID + base]      = f2bf(v1);
            Vrow[(size_t)tok * HID + base + 64] = f2bf(v2);
          }
        }
      }
    }
  }
}

// ---------------- causal flash attention v6: register-direct P ----------------
// Merged strip pairs (H=31-p, L=p share staged K/V prefix). Swapped QK^T puts
// P's q-row on l15 = exactly the PV A-operand's m=l15; lane's 16 in-register
// values fill A-slots k=lg*8+j / 32+lg*8+j under the token bit-perm baked
// into Vt -> P never touches LDS (8 cvt_pk -> two frag16).
__global__ __launch_bounds__(256, 2) void flash_attn6(
    const short* __restrict__ Qb, const short* __restrict__ Kb,
    const short* __restrict__ Vt, short* __restrict__ attn) {
  __shared__ alignas(16) short Klds[2][64 * 128];
  __shared__ alignas(16) short Vlds[2][128 * 64];

  const int tid = threadIdx.x;
  const int w = tid >> 6, lane = tid & 63;
  const int l15 = lane & 15, lg = lane >> 4;
  const int bid = blockIdx.x;
  const int p = bid >> 5;                  // 0..15: pair (31-p, p)
  const int bh = bid & 31;
  const int b = bh >> 4, h = bh & 15;

  frag16 ones;
#pragma unroll
  for (int j = 0; j < 8; j++) ones[j] = (short)0x3F80;

  auto stage = [&](int kv0, int buf) {
#pragma unroll
    for (int ci = 0; ci < 4; ci++) {
      int cc = w * 4 + ci;                 // 0..15
      int krow = cc * 4 + (lane >> 4);
      int kss = (lane & 15) ^ (krow & 15);
      GLDS(Kb + (size_t)(b * SEQ + kv0 + krow) * HID + h * HD + kss * 8,
           Klds[buf] + cc * 512);
      int vd = cc * 8 + (lane >> 3);
      int vss = (lane & 7) ^ (vd & 7);
      GLDS(Vt + (size_t)(h * HD + vd) * TT + b * SEQ + kv0 + vss * 8,
           Vlds[buf] + cc * 512);
    }
  };

  const int qrowH = (31 - p) * 64 + w * 16;
  const int qrowL = p * 64 + w * 16;
  const int ntH = 32 - p;                  // tiles for heavy strip

  frag16 qfH[4], qfL[4];
  {
    const short* qpH = Qb + (size_t)(b * SEQ + qrowH + l15) * HID + h * HD + lg * 8;
    const short* qpL = Qb + (size_t)(b * SEQ + qrowL + l15) * HID + h * HD + lg * 8;
#pragma unroll
    for (int ds = 0; ds < 4; ds++) {
      qfH[ds] = *(const frag16*)(qpH + ds * 32);
      qfL[ds] = *(const frag16*)(qpL + ds * 32);
    }
  }
  f32x4 oH[8], oL[8];
#pragma unroll
  for (int j = 0; j < 8; j++) { oH[j] = {0.f, 0.f, 0.f, 0.f}; oL[j] = {0.f, 0.f, 0.f, 0.f}; }
  f32x4 laH = {0.f, 0.f, 0.f, 0.f}, laL = {0.f, 0.f, 0.f, 0.f};
  float mrH = -1e30f, mrL = -1e30f;

  auto proc = [&](const frag16 (&qf)[4], f32x4 (&o)[8], f32x4& la, float& mr,
                  bool diag, const short* Kl, const short* Vl) {
    f32x4 sa[4];
#pragma unroll
    for (int f = 0; f < 4; f++) sa[f] = {0.f, 0.f, 0.f, 0.f};
    __builtin_amdgcn_s_setprio(1);
#pragma unroll
    for (int ds = 0; ds < 4; ds++) {
      int phys = (ds * 4 + lg) ^ l15;
#pragma unroll
      for (int f = 0; f < 4; f++) {
        frag16 kf = *(const frag16*)(Kl + (f * 16 + l15) * 128 + phys * 8);
        sa[f] = __builtin_amdgcn_mfma_f32_16x16x32_bf16(kf, qf[ds], sa[f], 0, 0, 0);
      }
    }
    __builtin_amdgcn_s_setprio(0);
    if (diag) {
      int ql = 16 * w + l15;
#pragma unroll
      for (int f = 0; f < 4; f++)
#pragma unroll
        for (int r = 0; r < 4; r++)
          if (f * 16 + lg * 4 + r > ql) sa[f][r] = -1e30f;
    }
    float pm = sa[0][0];
#pragma unroll
    for (int f = 0; f < 4; f++)
#pragma unroll
      for (int r = 0; r < 4; r++) pm = fmaxf(pm, sa[f][r]);
    pm = fmaxf(pm, __shfl_xor(pm, 16));
    pm = fmaxf(pm, __shfl_xor(pm, 32));
    if (__any(pm > mr + 8.f)) {
      float mn = fmaxf(mr, pm);
      float frl = exp2f(mr - mn);
      mr = mn;
      float fr4[4];
#pragma unroll
      for (int r = 0; r < 4; r++)
        fr4[r] = __shfl(frl, lg * 16 + lg * 4 + r);
#pragma unroll
      for (int r = 0; r < 4; r++) {
        la[r] *= fr4[r];
#pragma unroll
        for (int j = 0; j < 8; j++) o[j][r] *= fr4[r];
      }
    }
    float pe[4][4];
#pragma unroll
    for (int f = 0; f < 4; f++)
#pragma unroll
      for (int r = 0; r < 4; r++) pe[f][r] = exp2f(sa[f][r] - mr);
    // register-direct P: pf0 shorts j = pe[j>>2][j&3], pf1 = pe[2+(j>>2)][j&3]
    u32x4 w0, w1;
    w0[0] = cvtpk(pe[0][0], pe[0][1]); w0[1] = cvtpk(pe[0][2], pe[0][3]);
    w0[2] = cvtpk(pe[1][0], pe[1][1]); w0[3] = cvtpk(pe[1][2], pe[1][3]);
    w1[0] = cvtpk(pe[2][0], pe[2][1]); w1[1] = cvtpk(pe[2][2], pe[2][3]);
    w1[2] = cvtpk(pe[3][0], pe[3][1]); w1[3] = cvtpk(pe[3][2], pe[3][3]);
    frag16 pf0 = __builtin_bit_cast(frag16, w0);
    frag16 pf1 = __builtin_bit_cast(frag16, w1);
    __builtin_amdgcn_s_setprio(1);
    la = __builtin_amdgcn_mfma_f32_16x16x32_bf16(pf0, ones, la, 0, 0, 0);
    la = __builtin_amdgcn_mfma_f32_16x16x32_bf16(pf1, ones, la, 0, 0, 0);
#pragma unroll
    for (int j = 0; j < 8; j++) {
      int d = j * 16 + l15;
      int p0 = lg ^ (d & 7);
      int p1 = (4 + lg) ^ (d & 7);
      frag16 vf0 = *(const frag16*)(Vl + d * 64 + p0 * 8);
      frag16 vf1 = *(const frag16*)(Vl + d * 64 + p1 * 8);
      o[j] = __builtin_amdgcn_mfma_f32_16x16x32_bf16(pf0, vf0, o[j], 0, 0, 0);
      o[j] = __builtin_amdgcn_mfma_f32_16x16x32_bf16(pf1, vf1, o[j], 0, 0, 0);
    }
    __builtin_amdgcn_s_setprio(0);
  };

  stage(0, 0);
  __syncthreads();

  int cur = 0;
  for (int t = 0; t < ntH; t++) {
    if (t + 1 < ntH) stage((t + 1) * 64, cur ^ 1);
    const short* Kl = &Klds[cur][0];
    const short* Vl = &Vlds[cur][0];
    proc(qfH, oH, laH, mrH, t == ntH - 1, Kl, Vl);
    if (t <= p) proc(qfL, oL, laL, mrL, t == p, Kl, Vl);
    __syncthreads();
    cur ^= 1;
  }

  {
    float inv[4];
#pragma unroll
    for (int r = 0; r < 4; r++) inv[r] = 1.f / laH[r];
    short* op = attn + (size_t)(b * SEQ + qrowH + lg * 4) * HID + h * HD + l15;
#pragma unroll
    for (int j = 0; j < 8; j++)
#pragma unroll
      for (int r = 0; r < 4; r++)
        op[(size_t)r * HID + j * 16] = f2bf(oH[j][r] * inv[r]);
  }
  {
    float inv[4];
#pragma unroll
    for (int r = 0; r < 4; r++) inv[r] = 1.f / laL[r];
    short* op = attn + (size_t)(b * SEQ + qrowL + lg * 4) * HID + h * HD + l15;
#pragma unroll
    for (int j = 0; j < 8; j++)
#pragma unroll
      for (int r = 0; r < 4; r++)
        op[(size_t)r * HID + j * 16] = f2bf(oL[j][r] * inv[r]);
  }
}

// ---------------- launcher ----------------
extern "C" void kernel_launch(void* const* d_in, const int* in_sizes, int n_in,
                              void* d_out, int out_size, void* d_ws, size_t ws_size,
                              hipStream_t stream) {
  const float* hidden = (const float*)d_in[0];
  const float* cosb   = (const float*)d_in[1];
  const float* sinb   = (const float*)d_in[2];
  const float* wqkv   = (const float*)d_in[3];
  const float* bqkv   = (const float*)d_in[4];
  const float* wo     = (const float*)d_in[5];
  const int*   slots  = (const int*)d_in[9];

  float* out = (float*)d_out;
  float* kc  = out + (size_t)TT * HID;
  float* vc  = kc + (size_t)TT * HID;

  short* ws    = (short*)d_ws;
  short* Abf   = ws;                       // 8,388,608 shorts (reused as attnb)
  short* Wqkvt = Abf + 8388608;            // 12,582,912
  short* Wot   = Wqkvt + 12582912;         // 4,194,304
  short* Qb    = Wot + 4194304;            // 8,388,608
  short* Kb    = Qb + 8388608;             // 8,388,608
  short* Vrow  = Kb + 8388608;             // 8,388,608
  short* Vt    = Vrow + 8388608;           // 8,388,608
  short* attnb = Abf;                      // reuse (A dead after GEMM1)

  prep<<<8192 + 3072 + 1024, 256, 0, stream>>>(hidden, Abf, wqkv, Wqkvt, wo, Wot);
  gemm_bt<1><<<dim3(48, 32), 256, 0, stream>>>(
      Abf, Wqkvt, bqkv, nullptr, cosb, sinb, Qb, Kb, Vrow, TT, NQKV, HID);
  post<<<2048 + 4096, 256, 0, stream>>>(Kb, Vrow, Vt, slots, kc, vc);
  flash_attn6<<<512, 256, 0, stream>>>(Qb, Kb, Vt, attnb);
  gemm_bt<0><<<dim3(16, 32), 256, 0, stream>>>(
      attnb, Wot, nullptr, out, nullptr, nullptr, nullptr, nullptr, nullptr,
      TT, HID, HID);
}